// Round 10
// baseline (395.421 us; speedup 1.0000x reference)
//
#include <hip/hip_runtime.h>
#include <hip/hip_bf16.h>
#include <stdint.h>

typedef short short8 __attribute__((ext_vector_type(8)));
typedef short bf16x8 __attribute__((ext_vector_type(8)));
typedef float f32x4 __attribute__((ext_vector_type(4)));
typedef float f4 __attribute__((ext_vector_type(4)));
typedef float f32x8 __attribute__((ext_vector_type(8)));
typedef float f32x16 __attribute__((ext_vector_type(16)));
typedef unsigned int u32x2 __attribute__((ext_vector_type(2)));

constexpr int Bn = 16;     // batch
constexpr int C  = 256;    // channels
constexpr int NT = 1024;   // tokens
constexpr int NH = 8;      // heads
constexpr int INNER = 512;
constexpr int QKVD = 1536;

#define DEVFN __device__ __forceinline__

DEVFN unsigned short f2b_rne(float f) {
    uint32_t x; __builtin_memcpy(&x, &f, 4);
    return (unsigned short)((x + 0x7fffu + ((x >> 16) & 1u)) >> 16);
}
DEVFN float exp2_fast(float x) {
    float r; asm("v_exp_f32 %0, %1" : "=v"(r) : "v"(x)); return r;
}
DEVFN uint32_t cvtpk(float a, float b) {
    uint32_t r; asm("v_cvt_pk_bf16_f32 %0, %1, %2" : "=v"(r) : "v"(a), "v"(b)); return r;
}
DEVFN void permswap(uint32_t& a, uint32_t& b) {
    asm("v_permlane32_swap_b32 %0, %1" : "+v"(a), "+v"(b));
}
DEVFN void gload16(const void* g, void* l) {
    __builtin_amdgcn_global_load_lds((const __attribute__((address_space(1))) void*)g,
                                     (__attribute__((address_space(3))) void*)l, 16, 0, 0);
}

// ---------- prep: z=0 -> WqkvT bf16 [j'][256] (j' = which*512+h*64+d)
//                  z=1 -> WoutT bf16 [c][512]
//                  z>=2 -> x fp32 [b][c][t] -> xT bf16 [b][t][c]   (b = z-2)
__global__ __launch_bounds__(256) void prep(const float* __restrict__ Wqkv,
                                            const float* __restrict__ Wout,
                                            const float* __restrict__ x,
                                            short* __restrict__ WqkvT,
                                            short* __restrict__ WoutT,
                                            short* __restrict__ xT) {
    __shared__ float T[64][65];
    const int tid = threadIdx.x;
    const int z = blockIdx.z;
    if (z == 0) {
        if (blockIdx.y >= 4) return;
        int jb = blockIdx.x, cb = blockIdx.y;
        int jpb = jb * 64;
        int jorig0 = ((jpb >> 6) & 7) * 192 + (jpb >> 9) * 64;
        #pragma unroll
        for (int it = 0; it < 4; ++it) {
            int cc = (tid >> 4) + it * 16, d4 = (tid & 15) * 4;
            f4 v = *(const f4*)&Wqkv[(size_t)(cb * 64 + cc) * QKVD + jorig0 + d4];
            T[cc][d4] = v[0]; T[cc][d4 + 1] = v[1]; T[cc][d4 + 2] = v[2]; T[cc][d4 + 3] = v[3];
        }
        __syncthreads();
        int d = tid >> 2, cs = tid & 3;
        short8 o0, o1;
        #pragma unroll
        for (int k = 0; k < 8; ++k) o0[k] = (short)f2b_rne(T[cs * 16 + k][d]);
        #pragma unroll
        for (int k = 0; k < 8; ++k) o1[k] = (short)f2b_rne(T[cs * 16 + 8 + k][d]);
        short* orow = WqkvT + (size_t)(jpb + d) * C + cb * 64 + cs * 16;
        *(short8*)orow = o0; *(short8*)(orow + 8) = o1;
    } else if (z == 1) {
        if (blockIdx.x >= 4) return;
        int cb = blockIdx.x, ib = blockIdx.y;
        #pragma unroll
        for (int it = 0; it < 4; ++it) {
            int ii = (tid >> 4) + it * 16, c4 = (tid & 15) * 4;
            f4 v = *(const f4*)&Wout[(size_t)(ib * 64 + ii) * C + cb * 64 + c4];
            T[ii][c4] = v[0]; T[ii][c4 + 1] = v[1]; T[ii][c4 + 2] = v[2]; T[ii][c4 + 3] = v[3];
        }
        __syncthreads();
        int cL = tid >> 2, is = tid & 3;
        short8 o0, o1;
        #pragma unroll
        for (int k = 0; k < 8; ++k) o0[k] = (short)f2b_rne(T[is * 16 + k][cL]);
        #pragma unroll
        for (int k = 0; k < 8; ++k) o1[k] = (short)f2b_rne(T[is * 16 + 8 + k][cL]);
        short* orow = WoutT + (size_t)(cb * 64 + cL) * INNER + ib * 64 + is * 16;
        *(short8*)orow = o0; *(short8*)(orow + 8) = o1;
    } else {
        if (blockIdx.x >= 16 || blockIdx.y >= 4) return;
        int tb = blockIdx.x, cb = blockIdx.y, b = z - 2;
        const float* xb = x + (size_t)b * C * NT;
        #pragma unroll
        for (int it = 0; it < 4; ++it) {
            int cc = (tid >> 4) + it * 16, t4 = (tid & 15) * 4;
            f4 v = *(const f4*)&xb[(size_t)(cb * 64 + cc) * NT + tb * 64 + t4];
            T[cc][t4] = v[0]; T[cc][t4 + 1] = v[1]; T[cc][t4 + 2] = v[2]; T[cc][t4 + 3] = v[3];
        }
        __syncthreads();
        int tL = tid >> 2, cs = tid & 3;
        short8 o0, o1;
        #pragma unroll
        for (int k = 0; k < 8; ++k) o0[k] = (short)f2b_rne(T[cs * 16 + k][tL]);
        #pragma unroll
        for (int k = 0; k < 8; ++k) o1[k] = (short)f2b_rne(T[cs * 16 + 8 + k][tL]);
        short* orow = xT + ((size_t)b * NT + tb * 64 + tL) * C + cb * 64 + cs * 16;
        *(short8*)orow = o0; *(short8*)(orow + 8) = o1;
    }
}

// ---------- qkv_gemm: C[t][j'] = xT . WqkvT^T, +bias(perm). Q scaled by SCALE*log2e.
// j' blocks 0-7 (Q,K) -> qkv[t][j]; blocks 8-11 (V) -> written TRANSPOSED to Vt[hd][t].
__global__ __launch_bounds__(256) void qkv_gemm(const short* __restrict__ xT,
                                                const short* __restrict__ WqkvT,
                                                const float* __restrict__ bqkv,
                                                short* __restrict__ qkv,
                                                short* __restrict__ Vt) {
    __shared__ __align__(16) short As[128][64];
    __shared__ __align__(16) short Bs[128][64];
    const int tid = threadIdx.x, l = tid & 63, w = tid >> 6;
    const int l15 = l & 15, g = l >> 4;
    const int wr = w >> 1, wc = w & 1;
    const int lr = l >> 3, ls = l & 7;
    const int j0 = blockIdx.x * 128, t0 = blockIdx.y * 128, b = blockIdx.z;
    f32x4 acc[4][4] = {};
    const short* Ab = xT + ((size_t)b * NT + t0) * C;
    const short* Bb = WqkvT + (size_t)j0 * C;

    for (int k0 = 0; k0 < C; k0 += 64) {
        __syncthreads();
        #pragma unroll
        for (int i = 0; i < 4; ++i) {
            int r0 = w * 32 + i * 8;
            int row = r0 + lr;
            int slot = ls ^ (row & 7);
            gload16(Ab + (size_t)row * C + k0 + slot * 8, &As[r0][0]);
            gload16(Bb + (size_t)row * C + k0 + slot * 8, &Bs[r0][0]);
        }
        __syncthreads();
        bf16x8 a[4][2], bb[4][2];
        #pragma unroll
        for (int m = 0; m < 4; ++m) {
            int row = wr * 64 + m * 16 + l15;
            const char* base = (const char*)&As[row][0];
            #pragma unroll
            for (int kk = 0; kk < 2; ++kk)
                a[m][kk] = *(const bf16x8*)(base + (((kk * 4 + g) ^ (row & 7)) << 4));
        }
        #pragma unroll
        for (int n = 0; n < 4; ++n) {
            int row = wc * 64 + n * 16 + l15;
            const char* base = (const char*)&Bs[row][0];
            #pragma unroll
            for (int kk = 0; kk < 2; ++kk)
                bb[n][kk] = *(const bf16x8*)(base + (((kk * 4 + g) ^ (row & 7)) << 4));
        }
        #pragma unroll
        for (int m = 0; m < 4; ++m)
            #pragma unroll
            for (int n = 0; n < 4; ++n) {
                acc[m][n] = __builtin_amdgcn_mfma_f32_16x16x32_bf16(a[m][0], bb[n][0], acc[m][n], 0, 0, 0);
                acc[m][n] = __builtin_amdgcn_mfma_f32_16x16x32_bf16(a[m][1], bb[n][1], acc[m][n], 0, 0, 0);
            }
    }

    if (blockIdx.x < 8) {
        short* qb = qkv + ((size_t)b * NT + t0) * QKVD;
        #pragma unroll
        for (int n = 0; n < 4; ++n) {
            int j = j0 + wc * 64 + n * 16 + l15;
            int jorig = ((j >> 6) & 7) * 192 + (j >> 9) * 64 + (j & 63);
            float bias = bqkv[jorig];
            float scale = (j < 512) ? 0.18033688f : 1.0f;   // SCALE * log2(e) folded into Q
            #pragma unroll
            for (int m = 0; m < 4; ++m) {
                #pragma unroll
                for (int r = 0; r < 4; ++r) {
                    int t = wr * 64 + m * 16 + g * 4 + r;
                    qb[(size_t)t * QKVD + j] = (short)f2b_rne((acc[m][n][r] + bias) * scale);
                }
            }
        }
    } else {
        // V -> Vt[b][hd][t] (transposed write)
        short* Vb = Vt + (size_t)b * INNER * NT;
        #pragma unroll
        for (int n = 0; n < 4; ++n) {
            int j = j0 + wc * 64 + n * 16 + l15;               // 1024..1535
            int jorig = ((j >> 6) & 7) * 192 + (j >> 9) * 64 + (j & 63);
            float bias = bqkv[jorig];
            int vr = j - 1024;
            #pragma unroll
            for (int m = 0; m < 4; ++m) {
                int t = t0 + wr * 64 + m * 16 + g * 4;
                float v0 = acc[m][n][0] + bias, v1 = acc[m][n][1] + bias;
                float v2 = acc[m][n][2] + bias, v3 = acc[m][n][3] + bias;
                u32x2 u; u[0] = cvtpk(v0, v1); u[1] = cvtpk(v2, v3);
                *(u32x2*)(Vb + (size_t)vr * NT + t) = u;
            }
        }
    }
}

// ---------- attn: swapped-operand flash attention, 4-buffer LDS pipeline with
// DELAYED PV (T15): iter t runs QK(t) + softmax(t) + PV(t-1); PV(t-1) depends only
// on pa_prev/buf(t-1) so its MFMAs interleave under softmax(t)'s VALU stream.
// Fully unrolled so all buffer indices and the pa rotation are compile-time.
// 8 waves x 32 q-rows; no max tracking (log2 domain, |s| << 127).
__global__ __launch_bounds__(512, 4) void attn(const short* __restrict__ qkv,
                                               const short* __restrict__ Vt,
                                               short* __restrict__ res) {
    __shared__ __align__(16) short Kl[4][64][64];
    __shared__ __align__(16) short Vl[4][64][64];   // [d][key]
    const int tid = threadIdx.x, l = tid & 63, w = tid >> 6;   // w in [0,8)
    const int q31 = l & 31, hi = l >> 5;
    const int lr = l >> 3, ls = l & 7;
    // XCD-chunked swizzle (512 = 8*64, bijective)
    const int bid = blockIdx.x;
    const int work = (bid & 7) * 64 + (bid >> 3);
    const int pair = work >> 2, qq = work & 3;
    const int b = pair >> 3, h = pair & 7;

    const short* Kg = qkv + (size_t)b * NT * QKVD + 512 + h * 64;
    const short* Vg = Vt + ((size_t)b * INNER + h * 64) * NT;

    // Q fragments for this wave's 32 q-rows
    bf16x8 qf[4];
    {
        int q = qq * 256 + w * 32 + q31;
        const short* Qr = qkv + ((size_t)b * NT + q) * QKVD + h * 64 + hi * 8;
        #pragma unroll
        for (int s = 0; s < 4; ++s) qf[s] = *(const bf16x8*)(Qr + 16 * s);
    }

    f32x8 sumAcc = {};         // per-lane denominator partials
    f32x16 o0 = {}, o1 = {};   // D[d][q] for d 0-31 / 32-63, col = own q
    bf16x8 paP[4];             // P^T fragments of the PREVIOUS tile

    // stage one 64-key tile: per wave 1 K gload16 + 1 V gload16 (rows w*8+lr)
    #define STAGE(tile, buf)                                                              \
        {                                                                                 \
            int k0s = (tile) * 64;                                                        \
            int row = w * 8 + lr;                                                         \
            gload16(Kg + (size_t)(k0s + row) * QKVD + (ls ^ lr) * 8, &Kl[buf][w * 8][0]); \
            gload16(Vg + (size_t)row * NT + k0s + (ls ^ lr) * 8, &Vl[buf][w * 8][0]);     \
        }

    STAGE(0, 0)
    STAGE(1, 1)

    #pragma unroll
    for (int t = 0; t <= 16; ++t) {
        if (t < 15)       asm volatile("s_waitcnt vmcnt(2)" ::: "memory");
        else if (t == 15) asm volatile("s_waitcnt vmcnt(0)" ::: "memory");
        if (t < 16) __builtin_amdgcn_s_barrier();   // publish tile t
        if (t < 14) STAGE(t + 2, (t + 2) & 3)

        // QK^T for tile t (2 independent chains)
        f32x16 s0 = {}, s1 = {};
        if (t < 16) {
            const char* kb = (const char*)&Kl[t & 3][0][0];
            bf16x8 kf0[4], kf1[4];
            #pragma unroll
            for (int s = 0; s < 4; ++s) {
                kf0[s] = *(const bf16x8*)(kb + q31 * 128 + (((s * 2 + hi) ^ (q31 & 7)) << 4));
                kf1[s] = *(const bf16x8*)(kb + (32 + q31) * 128 + (((s * 2 + hi) ^ (q31 & 7)) << 4));
            }
            #pragma unroll
            for (int s = 0; s < 4; ++s) {
                s0 = __builtin_amdgcn_mfma_f32_32x32x16_bf16(kf0[s], qf[s], s0, 0, 0, 0);
                s1 = __builtin_amdgcn_mfma_f32_32x32x16_bf16(kf1[s], qf[s], s1, 0, 0, 0);
            }
        }

        // PV for tile t-1: reads V from buf (t-1)&3 (still intact; overwritten only
        // at iter t+1's STAGE, which is after the next barrier) + paP from last iter.
        // Independent of softmax(t) below -> MFMA/VALU co-issue.
        if (t >= 1) {
            const char* vb = (const char*)&Vl[(t - 1) & 3][0][0];
            bf16x8 vf0[4], vf1[4];
            #pragma unroll
            for (int kc = 0; kc < 4; ++kc) {
                vf0[kc] = *(const bf16x8*)(vb + q31 * 128 + (((kc * 2 + hi) ^ (q31 & 7)) << 4));
                vf1[kc] = *(const bf16x8*)(vb + (32 + q31) * 128 + (((kc * 2 + hi) ^ (q31 & 7)) << 4));
            }
            #pragma unroll
            for (int kc = 0; kc < 4; ++kc) {
                o0 = __builtin_amdgcn_mfma_f32_32x32x16_bf16(vf0[kc], paP[kc], o0, 0, 0, 0);
                o1 = __builtin_amdgcn_mfma_f32_32x32x16_bf16(vf1[kc], paP[kc], o1, 0, 0, 0);
            }
        }

        // softmax(t) -> paP (consumed next iter)
        if (t < 16) {
            #pragma unroll
            for (int r = 0; r < 16; ++r) { s0[r] = exp2_fast(s0[r]); s1[r] = exp2_fast(s1[r]); }
            #pragma unroll
            for (int r = 0; r < 8; ++r) sumAcc[r] += (s0[r] + s0[r + 8]) + (s1[r] + s1[r + 8]);
            #pragma unroll
            for (int kc = 0; kc < 4; ++kc) {
                uint32_t w0, w1, w2, w3;
                if (kc < 2) {
                    const int i0 = (kc & 1) * 8;
                    w0 = cvtpk(s0[i0 + 0], s0[i0 + 1]); w2 = cvtpk(s0[i0 + 4], s0[i0 + 5]);
                    w1 = cvtpk(s0[i0 + 2], s0[i0 + 3]); w3 = cvtpk(s0[i0 + 6], s0[i0 + 7]);
                } else {
                    const int i0 = (kc & 1) * 8;
                    w0 = cvtpk(s1[i0 + 0], s1[i0 + 1]); w2 = cvtpk(s1[i0 + 4], s1[i0 + 5]);
                    w1 = cvtpk(s1[i0 + 2], s1[i0 + 3]); w3 = cvtpk(s1[i0 + 6], s1[i0 + 7]);
                }
                permswap(w0, w2); permswap(w1, w3);
                uint32_t pw[4] = {w0, w1, w2, w3};
                __builtin_memcpy(&paP[kc], pw, 16);
            }
        }
    }
    #undef STAGE

    // epilogue: denominator + normalized bf16 stores
    float sm[8];
    #pragma unroll
    for (int r = 0; r < 8; ++r) sm[r] = sumAcc[r];
    #pragma unroll
    for (int stp = 4; stp > 0; stp >>= 1)
        #pragma unroll
        for (int r = 0; r < stp; ++r) sm[r] += sm[r + stp];
    float lR = sm[0] + __shfl_xor(sm[0], 32, 64);
    const float inv = 1.0f / lR;
    int q = qq * 256 + w * 32 + q31;
    short* rb = res + ((size_t)b * NT + q) * INNER + h * 64 + hi * 4;
    #pragma unroll
    for (int g2 = 0; g2 < 4; ++g2) {
        u32x2 u;
        u[0] = cvtpk(o0[4 * g2 + 0] * inv, o0[4 * g2 + 1] * inv);
        u[1] = cvtpk(o0[4 * g2 + 2] * inv, o0[4 * g2 + 3] * inv);
        *(u32x2*)(rb + 8 * g2) = u;
        u32x2 u2;
        u2[0] = cvtpk(o1[4 * g2 + 0] * inv, o1[4 * g2 + 1] * inv);
        u2[1] = cvtpk(o1[4 * g2 + 2] * inv, o1[4 * g2 + 3] * inv);
        *(u32x2*)(rb + 32 + 8 * g2) = u2;
    }
}

// ---------- out_proj: out[b][c][t] = (Wout^T.res^T)[c][t] + bout[c] + x[b][c][t]
__global__ __launch_bounds__(256) void out_proj(const short* __restrict__ WoutT,
                                                const short* __restrict__ res,
                                                const float* __restrict__ bout,
                                                const float* __restrict__ x,
                                                float* __restrict__ out) {
    __shared__ __align__(16) short As[128][64];   // WoutT rows (c)
    __shared__ __align__(16) short Bs[128][64];   // res rows (t)
    const int tid = threadIdx.x, l = tid & 63, w = tid >> 6;
    const int l15 = l & 15, g = l >> 4;
    const int wr = w >> 1, wc = w & 1;
    const int lr = l >> 3, ls = l & 7;
    const int t0 = blockIdx.x * 128, c0 = blockIdx.y * 128, b = blockIdx.z;
    f32x4 acc[4][4] = {};
    const short* Ab = WoutT + (size_t)c0 * INNER;
    const short* Bb = res + ((size_t)b * NT + t0) * INNER;

    for (int k0 = 0; k0 < INNER; k0 += 64) {
        __syncthreads();
        #pragma unroll
        for (int i = 0; i < 4; ++i) {
            int r0 = w * 32 + i * 8;
            int row = r0 + lr;
            int slot = ls ^ (row & 7);
            gload16(Ab + (size_t)row * INNER + k0 + slot * 8, &As[r0][0]);
            gload16(Bb + (size_t)row * INNER + k0 + slot * 8, &Bs[r0][0]);
        }
        __syncthreads();
        bf16x8 a[4][2], bb[4][2];
        #pragma unroll
        for (int m = 0; m < 4; ++m) {
            int row = wr * 64 + m * 16 + l15;
            const char* base = (const char*)&As[row][0];
            #pragma unroll
            for (int kk = 0; kk < 2; ++kk)
                a[m][kk] = *(const bf16x8*)(base + (((kk * 4 + g) ^ (row & 7)) << 4));
        }
        #pragma unroll
        for (int n = 0; n < 4; ++n) {
            int row = wc * 64 + n * 16 + l15;
            const char* base = (const char*)&Bs[row][0];
            #pragma unroll
            for (int kk = 0; kk < 2; ++kk)
                bb[n][kk] = *(const bf16x8*)(base + (((kk * 4 + g) ^ (row & 7)) << 4));
        }
        #pragma unroll
        for (int m = 0; m < 4; ++m)
            #pragma unroll
            for (int n = 0; n < 4; ++n) {
                acc[m][n] = __builtin_amdgcn_mfma_f32_16x16x32_bf16(a[m][0], bb[n][0], acc[m][n], 0, 0, 0);
                acc[m][n] = __builtin_amdgcn_mfma_f32_16x16x32_bf16(a[m][1], bb[n][1], acc[m][n], 0, 0, 0);
            }
    }

    const float* xb = x + (size_t)b * C * NT;
    float* ob = out + (size_t)b * C * NT;
    #pragma unroll
    for (int m = 0; m < 4; ++m) {
        #pragma unroll
        for (int r = 0; r < 4; ++r) {
            int c = c0 + wr * 64 + m * 16 + g * 4 + r;
            float bias = bout[c];
            #pragma unroll
            for (int n = 0; n < 4; ++n) {
                int t = t0 + wc * 64 + n * 16 + l15;
                size_t idx = (size_t)c * NT + t;
                ob[idx] = acc[m][n][r] + bias + xb[idx];
            }
        }
    }
}

extern "C" void kernel_launch(void* const* d_in, const int* in_sizes, int n_in,
                              void* d_out, int out_size, void* d_ws, size_t ws_size,
                              hipStream_t stream) {
    const float* x    = (const float*)d_in[0];
    const float* Wqkv = (const float*)d_in[1];
    const float* bqkv = (const float*)d_in[2];
    const float* Wout = (const float*)d_in[3];
    const float* bout = (const float*)d_in[4];
    float* out = (float*)d_out;

    char* ws = (char*)d_ws;
    short* qkvb  = (short*)(ws);                       // 50,331,648 B (V third unused)
    short* VtB   = (short*)(ws + 50331648);            // 16,777,216 B
    short* xTres = (short*)(ws + 67108864);            // 16,777,216 B (xT then res)
    short* WqT   = (short*)(ws + 83886080);            //    786,432 B
    short* WoT   = (short*)(ws + 84672512);            //    262,144 B

    prep<<<dim3(24, 8, 18), 256, 0, stream>>>(Wqkv, Wout, x, WqT, WoT, xTres);
    qkv_gemm<<<dim3(12, 8, 16), 256, 0, stream>>>(xTres, WqT, bqkv, qkvb, VtB);
    attn<<<dim3(512, 1, 1), 512, 0, stream>>>(qkvb, VtB, xTres);
    out_proj<<<dim3(8, 2, 16), 256, 0, stream>>>(WoT, xTres, bout, x, out);
}

// Round 11
// 95.084 us; speedup vs baseline: 4.1587x; 4.1587x over previous
//
#include <hip/hip_runtime.h>
#include <hip/hip_bf16.h>
#include <stdint.h>

typedef short short8 __attribute__((ext_vector_type(8)));
typedef short bf16x8 __attribute__((ext_vector_type(8)));
typedef float f32x4 __attribute__((ext_vector_type(4)));
typedef float f4 __attribute__((ext_vector_type(4)));
typedef float f32x8 __attribute__((ext_vector_type(8)));
typedef float f32x16 __attribute__((ext_vector_type(16)));
typedef unsigned int u32x2 __attribute__((ext_vector_type(2)));

constexpr int Bn = 16;     // batch
constexpr int C  = 256;    // channels
constexpr int NT = 1024;   // tokens
constexpr int NH = 8;      // heads
constexpr int INNER = 512;
constexpr int QKVD = 1536;

#define DEVFN __device__ __forceinline__

DEVFN unsigned short f2b_rne(float f) {
    uint32_t x; __builtin_memcpy(&x, &f, 4);
    return (unsigned short)((x + 0x7fffu + ((x >> 16) & 1u)) >> 16);
}
DEVFN float exp2_fast(float x) {
    float r; asm("v_exp_f32 %0, %1" : "=v"(r) : "v"(x)); return r;
}
DEVFN uint32_t cvtpk(float a, float b) {
    uint32_t r; asm("v_cvt_pk_bf16_f32 %0, %1, %2" : "=v"(r) : "v"(a), "v"(b)); return r;
}
DEVFN void permswap(uint32_t& a, uint32_t& b) {
    asm("v_permlane32_swap_b32 %0, %1" : "+v"(a), "+v"(b));
}
DEVFN void gload16(const void* g, void* l) {
    __builtin_amdgcn_global_load_lds((const __attribute__((address_space(1))) void*)g,
                                     (__attribute__((address_space(3))) void*)l, 16, 0, 0);
}

// ---------- prep: z=0 -> WqkvT bf16 [j'][256] (j' = which*512+h*64+d)
//                  z=1 -> WoutT bf16 [c][512]
//                  z>=2 -> x fp32 [b][c][t] -> xT bf16 [b][t][c]   (b = z-2)
__global__ __launch_bounds__(256) void prep(const float* __restrict__ Wqkv,
                                            const float* __restrict__ Wout,
                                            const float* __restrict__ x,
                                            short* __restrict__ WqkvT,
                                            short* __restrict__ WoutT,
                                            short* __restrict__ xT) {
    __shared__ float T[64][65];
    const int tid = threadIdx.x;
    const int z = blockIdx.z;
    if (z == 0) {
        if (blockIdx.y >= 4) return;
        int jb = blockIdx.x, cb = blockIdx.y;
        int jpb = jb * 64;
        int jorig0 = ((jpb >> 6) & 7) * 192 + (jpb >> 9) * 64;
        #pragma unroll
        for (int it = 0; it < 4; ++it) {
            int cc = (tid >> 4) + it * 16, d4 = (tid & 15) * 4;
            f4 v = *(const f4*)&Wqkv[(size_t)(cb * 64 + cc) * QKVD + jorig0 + d4];
            T[cc][d4] = v[0]; T[cc][d4 + 1] = v[1]; T[cc][d4 + 2] = v[2]; T[cc][d4 + 3] = v[3];
        }
        __syncthreads();
        int d = tid >> 2, cs = tid & 3;
        short8 o0, o1;
        #pragma unroll
        for (int k = 0; k < 8; ++k) o0[k] = (short)f2b_rne(T[cs * 16 + k][d]);
        #pragma unroll
        for (int k = 0; k < 8; ++k) o1[k] = (short)f2b_rne(T[cs * 16 + 8 + k][d]);
        short* orow = WqkvT + (size_t)(jpb + d) * C + cb * 64 + cs * 16;
        *(short8*)orow = o0; *(short8*)(orow + 8) = o1;
    } else if (z == 1) {
        if (blockIdx.x >= 4) return;
        int cb = blockIdx.x, ib = blockIdx.y;
        #pragma unroll
        for (int it = 0; it < 4; ++it) {
            int ii = (tid >> 4) + it * 16, c4 = (tid & 15) * 4;
            f4 v = *(const f4*)&Wout[(size_t)(ib * 64 + ii) * C + cb * 64 + c4];
            T[ii][c4] = v[0]; T[ii][c4 + 1] = v[1]; T[ii][c4 + 2] = v[2]; T[ii][c4 + 3] = v[3];
        }
        __syncthreads();
        int cL = tid >> 2, is = tid & 3;
        short8 o0, o1;
        #pragma unroll
        for (int k = 0; k < 8; ++k) o0[k] = (short)f2b_rne(T[is * 16 + k][cL]);
        #pragma unroll
        for (int k = 0; k < 8; ++k) o1[k] = (short)f2b_rne(T[is * 16 + 8 + k][cL]);
        short* orow = WoutT + (size_t)(cb * 64 + cL) * INNER + ib * 64 + is * 16;
        *(short8*)orow = o0; *(short8*)(orow + 8) = o1;
    } else {
        if (blockIdx.x >= 16 || blockIdx.y >= 4) return;
        int tb = blockIdx.x, cb = blockIdx.y, b = z - 2;
        const float* xb = x + (size_t)b * C * NT;
        #pragma unroll
        for (int it = 0; it < 4; ++it) {
            int cc = (tid >> 4) + it * 16, t4 = (tid & 15) * 4;
            f4 v = *(const f4*)&xb[(size_t)(cb * 64 + cc) * NT + tb * 64 + t4];
            T[cc][t4] = v[0]; T[cc][t4 + 1] = v[1]; T[cc][t4 + 2] = v[2]; T[cc][t4 + 3] = v[3];
        }
        __syncthreads();
        int tL = tid >> 2, cs = tid & 3;
        short8 o0, o1;
        #pragma unroll
        for (int k = 0; k < 8; ++k) o0[k] = (short)f2b_rne(T[cs * 16 + k][tL]);
        #pragma unroll
        for (int k = 0; k < 8; ++k) o1[k] = (short)f2b_rne(T[cs * 16 + 8 + k][tL]);
        short* orow = xT + ((size_t)b * NT + tb * 64 + tL) * C + cb * 64 + cs * 16;
        *(short8*)orow = o0; *(short8*)(orow + 8) = o1;
    }
}

// ---------- qkv_gemm: C[t][j'] = xT . WqkvT^T, +bias(perm). Q scaled by SCALE*log2e.
// j' blocks 0-7 (Q,K) -> qkv[t][j]; blocks 8-11 (V) -> written TRANSPOSED to Vt[hd][t].
__global__ __launch_bounds__(256) void qkv_gemm(const short* __restrict__ xT,
                                                const short* __restrict__ WqkvT,
                                                const float* __restrict__ bqkv,
                                                short* __restrict__ qkv,
                                                short* __restrict__ Vt) {
    __shared__ __align__(16) short As[128][64];
    __shared__ __align__(16) short Bs[128][64];
    const int tid = threadIdx.x, l = tid & 63, w = tid >> 6;
    const int l15 = l & 15, g = l >> 4;
    const int wr = w >> 1, wc = w & 1;
    const int lr = l >> 3, ls = l & 7;
    const int j0 = blockIdx.x * 128, t0 = blockIdx.y * 128, b = blockIdx.z;
    f32x4 acc[4][4] = {};
    const short* Ab = xT + ((size_t)b * NT + t0) * C;
    const short* Bb = WqkvT + (size_t)j0 * C;

    for (int k0 = 0; k0 < C; k0 += 64) {
        __syncthreads();
        #pragma unroll
        for (int i = 0; i < 4; ++i) {
            int r0 = w * 32 + i * 8;
            int row = r0 + lr;
            int slot = ls ^ (row & 7);
            gload16(Ab + (size_t)row * C + k0 + slot * 8, &As[r0][0]);
            gload16(Bb + (size_t)row * C + k0 + slot * 8, &Bs[r0][0]);
        }
        __syncthreads();
        bf16x8 a[4][2], bb[4][2];
        #pragma unroll
        for (int m = 0; m < 4; ++m) {
            int row = wr * 64 + m * 16 + l15;
            const char* base = (const char*)&As[row][0];
            #pragma unroll
            for (int kk = 0; kk < 2; ++kk)
                a[m][kk] = *(const bf16x8*)(base + (((kk * 4 + g) ^ (row & 7)) << 4));
        }
        #pragma unroll
        for (int n = 0; n < 4; ++n) {
            int row = wc * 64 + n * 16 + l15;
            const char* base = (const char*)&Bs[row][0];
            #pragma unroll
            for (int kk = 0; kk < 2; ++kk)
                bb[n][kk] = *(const bf16x8*)(base + (((kk * 4 + g) ^ (row & 7)) << 4));
        }
        #pragma unroll
        for (int m = 0; m < 4; ++m)
            #pragma unroll
            for (int n = 0; n < 4; ++n) {
                acc[m][n] = __builtin_amdgcn_mfma_f32_16x16x32_bf16(a[m][0], bb[n][0], acc[m][n], 0, 0, 0);
                acc[m][n] = __builtin_amdgcn_mfma_f32_16x16x32_bf16(a[m][1], bb[n][1], acc[m][n], 0, 0, 0);
            }
    }

    if (blockIdx.x < 8) {
        short* qb = qkv + ((size_t)b * NT + t0) * QKVD;
        #pragma unroll
        for (int n = 0; n < 4; ++n) {
            int j = j0 + wc * 64 + n * 16 + l15;
            int jorig = ((j >> 6) & 7) * 192 + (j >> 9) * 64 + (j & 63);
            float bias = bqkv[jorig];
            float scale = (j < 512) ? 0.18033688f : 1.0f;   // SCALE * log2(e) folded into Q
            #pragma unroll
            for (int m = 0; m < 4; ++m) {
                #pragma unroll
                for (int r = 0; r < 4; ++r) {
                    int t = wr * 64 + m * 16 + g * 4 + r;
                    qb[(size_t)t * QKVD + j] = (short)f2b_rne((acc[m][n][r] + bias) * scale);
                }
            }
        }
    } else {
        // V -> Vt[b][hd][t] (transposed write)
        short* Vb = Vt + (size_t)b * INNER * NT;
        #pragma unroll
        for (int n = 0; n < 4; ++n) {
            int j = j0 + wc * 64 + n * 16 + l15;               // 1024..1535
            int jorig = ((j >> 6) & 7) * 192 + (j >> 9) * 64 + (j & 63);
            float bias = bqkv[jorig];
            int vr = j - 1024;
            #pragma unroll
            for (int m = 0; m < 4; ++m) {
                int t = t0 + wr * 64 + m * 16 + g * 4;
                float v0 = acc[m][n][0] + bias, v1 = acc[m][n][1] + bias;
                float v2 = acc[m][n][2] + bias, v3 = acc[m][n][3] + bias;
                u32x2 u; u[0] = cvtpk(v0, v1); u[1] = cvtpk(v2, v3);
                *(u32x2*)(Vb + (size_t)vr * NT + t) = u;
            }
        }
    }
}

// ---------- attn: swapped-operand flash attention, 4-buffer LDS pipeline with
// ROLLED delayed-PV (T15): iter t runs QK(t), PV(t-1) (independent of softmax(t)),
// softmax(t)->paP. Buffer safety: PV(t-1) reads buf (t-1)&3; STAGE at iter t writes
// (t+2)&3 != (t-1)&3 (mod 4), and barrier rendezvous guarantees prior reads retired.
// 8 waves x 32 q-rows; no max tracking (log2 domain, |s| << 127).
__global__ __launch_bounds__(512, 4) void attn(const short* __restrict__ qkv,
                                               const short* __restrict__ Vt,
                                               short* __restrict__ res) {
    __shared__ __align__(16) short Kl[4][64][64];
    __shared__ __align__(16) short Vl[4][64][64];   // [d][key]
    const int tid = threadIdx.x, l = tid & 63, w = tid >> 6;   // w in [0,8)
    const int q31 = l & 31, hi = l >> 5;
    const int lr = l >> 3, ls = l & 7;
    // XCD-chunked swizzle (512 = 8*64, bijective)
    const int bid = blockIdx.x;
    const int work = (bid & 7) * 64 + (bid >> 3);
    const int pair = work >> 2, qq = work & 3;
    const int b = pair >> 3, h = pair & 7;

    const short* Kg = qkv + (size_t)b * NT * QKVD + 512 + h * 64;
    const short* Vg = Vt + ((size_t)b * INNER + h * 64) * NT;

    // Q fragments for this wave's 32 q-rows
    bf16x8 qf[4];
    {
        int q = qq * 256 + w * 32 + q31;
        const short* Qr = qkv + ((size_t)b * NT + q) * QKVD + h * 64 + hi * 8;
        #pragma unroll
        for (int s = 0; s < 4; ++s) qf[s] = *(const bf16x8*)(Qr + 16 * s);
    }

    f32x8 sumAcc = {};         // per-lane denominator partials
    f32x16 o0 = {}, o1 = {};   // D[d][q] for d 0-31 / 32-63, col = own q
    bf16x8 paP[4];             // P^T fragments of the PREVIOUS tile

    // stage one 64-key tile: per wave 1 K gload16 + 1 V gload16 (rows w*8+lr)
    #define STAGE(tile, buf)                                                              \
        {                                                                                 \
            int k0s = (tile) * 64;                                                        \
            int row = w * 8 + lr;                                                         \
            gload16(Kg + (size_t)(k0s + row) * QKVD + (ls ^ lr) * 8, &Kl[buf][w * 8][0]); \
            gload16(Vg + (size_t)row * NT + k0s + (ls ^ lr) * 8, &Vl[buf][w * 8][0]);     \
        }

    STAGE(0, 0)
    STAGE(1, 1)

    for (int t = 0; t < 16; ++t) {
        // retire tile t's 2 staging loads (oldest), leave tile t+1's in flight
        if (t < 15) asm volatile("s_waitcnt vmcnt(2)" ::: "memory");
        else        asm volatile("s_waitcnt vmcnt(0)" ::: "memory");
        __builtin_amdgcn_s_barrier();   // publish tile t to all waves
        if (t < 14) STAGE(t + 2, (t + 2) & 3)

        // QK^T for tile t (2 independent chains)
        const char* kb = (const char*)&Kl[t & 3][0][0];
        bf16x8 kf0[4], kf1[4];
        #pragma unroll
        for (int s = 0; s < 4; ++s) {
            kf0[s] = *(const bf16x8*)(kb + q31 * 128 + (((s * 2 + hi) ^ (q31 & 7)) << 4));
            kf1[s] = *(const bf16x8*)(kb + (32 + q31) * 128 + (((s * 2 + hi) ^ (q31 & 7)) << 4));
        }
        f32x16 s0 = {}, s1 = {};
        #pragma unroll
        for (int s = 0; s < 4; ++s) {
            s0 = __builtin_amdgcn_mfma_f32_32x32x16_bf16(kf0[s], qf[s], s0, 0, 0, 0);
            s1 = __builtin_amdgcn_mfma_f32_32x32x16_bf16(kf1[s], qf[s], s1, 0, 0, 0);
        }

        // PV for tile t-1 (uses paP + V buffer (t-1)&3) — independent of softmax(t)
        if (t >= 1) {
            const char* vb = (const char*)&Vl[(t - 1) & 3][0][0];
            bf16x8 vf0[4], vf1[4];
            #pragma unroll
            for (int kc = 0; kc < 4; ++kc) {
                vf0[kc] = *(const bf16x8*)(vb + q31 * 128 + (((kc * 2 + hi) ^ (q31 & 7)) << 4));
                vf1[kc] = *(const bf16x8*)(vb + (32 + q31) * 128 + (((kc * 2 + hi) ^ (q31 & 7)) << 4));
            }
            #pragma unroll
            for (int kc = 0; kc < 4; ++kc) {
                o0 = __builtin_amdgcn_mfma_f32_32x32x16_bf16(vf0[kc], paP[kc], o0, 0, 0, 0);
                o1 = __builtin_amdgcn_mfma_f32_32x32x16_bf16(vf1[kc], paP[kc], o1, 0, 0, 0);
            }
        }

        // softmax(t) -> paP (consumed next iter); overlaps PV(t-1) MFMAs above
        #pragma unroll
        for (int r = 0; r < 16; ++r) { s0[r] = exp2_fast(s0[r]); s1[r] = exp2_fast(s1[r]); }
        #pragma unroll
        for (int r = 0; r < 8; ++r) sumAcc[r] += (s0[r] + s0[r + 8]) + (s1[r] + s1[r + 8]);
        #pragma unroll
        for (int kc = 0; kc < 4; ++kc) {
            uint32_t w0, w1, w2, w3;
            if (kc < 2) {
                const int i0 = (kc & 1) * 8;
                w0 = cvtpk(s0[i0 + 0], s0[i0 + 1]); w2 = cvtpk(s0[i0 + 4], s0[i0 + 5]);
                w1 = cvtpk(s0[i0 + 2], s0[i0 + 3]); w3 = cvtpk(s0[i0 + 6], s0[i0 + 7]);
            } else {
                const int i0 = (kc & 1) * 8;
                w0 = cvtpk(s1[i0 + 0], s1[i0 + 1]); w2 = cvtpk(s1[i0 + 4], s1[i0 + 5]);
                w1 = cvtpk(s1[i0 + 2], s1[i0 + 3]); w3 = cvtpk(s1[i0 + 6], s1[i0 + 7]);
            }
            permswap(w0, w2); permswap(w1, w3);
            uint32_t pw[4] = {w0, w1, w2, w3};
            __builtin_memcpy(&paP[kc], pw, 16);
        }
    }
    #undef STAGE

    // epilogue: PV for tile 15 (buffer 15&3 = 3)
    {
        const char* vb = (const char*)&Vl[3][0][0];
        bf16x8 vf0[4], vf1[4];
        #pragma unroll
        for (int kc = 0; kc < 4; ++kc) {
            vf0[kc] = *(const bf16x8*)(vb + q31 * 128 + (((kc * 2 + hi) ^ (q31 & 7)) << 4));
            vf1[kc] = *(const bf16x8*)(vb + (32 + q31) * 128 + (((kc * 2 + hi) ^ (q31 & 7)) << 4));
        }
        #pragma unroll
        for (int kc = 0; kc < 4; ++kc) {
            o0 = __builtin_amdgcn_mfma_f32_32x32x16_bf16(vf0[kc], paP[kc], o0, 0, 0, 0);
            o1 = __builtin_amdgcn_mfma_f32_32x32x16_bf16(vf1[kc], paP[kc], o1, 0, 0, 0);
        }
    }

    // epilogue: denominator + normalized bf16 stores
    float sm[8];
    #pragma unroll
    for (int r = 0; r < 8; ++r) sm[r] = sumAcc[r];
    #pragma unroll
    for (int stp = 4; stp > 0; stp >>= 1)
        #pragma unroll
        for (int r = 0; r < stp; ++r) sm[r] += sm[r + stp];
    float lR = sm[0] + __shfl_xor(sm[0], 32, 64);
    const float inv = 1.0f / lR;
    int q = qq * 256 + w * 32 + q31;
    short* rb = res + ((size_t)b * NT + q) * INNER + h * 64 + hi * 4;
    #pragma unroll
    for (int g2 = 0; g2 < 4; ++g2) {
        u32x2 u;
        u[0] = cvtpk(o0[4 * g2 + 0] * inv, o0[4 * g2 + 1] * inv);
        u[1] = cvtpk(o0[4 * g2 + 2] * inv, o0[4 * g2 + 3] * inv);
        *(u32x2*)(rb + 8 * g2) = u;
        u32x2 u2;
        u2[0] = cvtpk(o1[4 * g2 + 0] * inv, o1[4 * g2 + 1] * inv);
        u2[1] = cvtpk(o1[4 * g2 + 2] * inv, o1[4 * g2 + 3] * inv);
        *(u32x2*)(rb + 32 + 8 * g2) = u2;
    }
}

// ---------- out_proj: out[b][c][t] = (Wout^T.res^T)[c][t] + bout[c] + x[b][c][t]
__global__ __launch_bounds__(256) void out_proj(const short* __restrict__ WoutT,
                                                const short* __restrict__ res,
                                                const float* __restrict__ bout,
                                                const float* __restrict__ x,
                                                float* __restrict__ out) {
    __shared__ __align__(16) short As[128][64];   // WoutT rows (c)
    __shared__ __align__(16) short Bs[128][64];   // res rows (t)
    const int tid = threadIdx.x, l = tid & 63, w = tid >> 6;
    const int l15 = l & 15, g = l >> 4;
    const int wr = w >> 1, wc = w & 1;
    const int lr = l >> 3, ls = l & 7;
    const int t0 = blockIdx.x * 128, c0 = blockIdx.y * 128, b = blockIdx.z;
    f32x4 acc[4][4] = {};
    const short* Ab = WoutT + (size_t)c0 * INNER;
    const short* Bb = res + ((size_t)b * NT + t0) * INNER;

    for (int k0 = 0; k0 < INNER; k0 += 64) {
        __syncthreads();
        #pragma unroll
        for (int i = 0; i < 4; ++i) {
            int r0 = w * 32 + i * 8;
            int row = r0 + lr;
            int slot = ls ^ (row & 7);
            gload16(Ab + (size_t)row * INNER + k0 + slot * 8, &As[r0][0]);
            gload16(Bb + (size_t)row * INNER + k0 + slot * 8, &Bs[r0][0]);
        }
        __syncthreads();
        bf16x8 a[4][2], bb[4][2];
        #pragma unroll
        for (int m = 0; m < 4; ++m) {
            int row = wr * 64 + m * 16 + l15;
            const char* base = (const char*)&As[row][0];
            #pragma unroll
            for (int kk = 0; kk < 2; ++kk)
                a[m][kk] = *(const bf16x8*)(base + (((kk * 4 + g) ^ (row & 7)) << 4));
        }
        #pragma unroll
        for (int n = 0; n < 4; ++n) {
            int row = wc * 64 + n * 16 + l15;
            const char* base = (const char*)&Bs[row][0];
            #pragma unroll
            for (int kk = 0; kk < 2; ++kk)
                bb[n][kk] = *(const bf16x8*)(base + (((kk * 4 + g) ^ (row & 7)) << 4));
        }
        #pragma unroll
        for (int m = 0; m < 4; ++m)
            #pragma unroll
            for (int n = 0; n < 4; ++n) {
                acc[m][n] = __builtin_amdgcn_mfma_f32_16x16x32_bf16(a[m][0], bb[n][0], acc[m][n], 0, 0, 0);
                acc[m][n] = __builtin_amdgcn_mfma_f32_16x16x32_bf16(a[m][1], bb[n][1], acc[m][n], 0, 0, 0);
            }
    }

    const float* xb = x + (size_t)b * C * NT;
    float* ob = out + (size_t)b * C * NT;
    #pragma unroll
    for (int m = 0; m < 4; ++m) {
        #pragma unroll
        for (int r = 0; r < 4; ++r) {
            int c = c0 + wr * 64 + m * 16 + g * 4 + r;
            float bias = bout[c];
            #pragma unroll
            for (int n = 0; n < 4; ++n) {
                int t = t0 + wc * 64 + n * 16 + l15;
                size_t idx = (size_t)c * NT + t;
                ob[idx] = acc[m][n][r] + bias + xb[idx];
            }
        }
    }
}

extern "C" void kernel_launch(void* const* d_in, const int* in_sizes, int n_in,
                              void* d_out, int out_size, void* d_ws, size_t ws_size,
                              hipStream_t stream) {
    const float* x    = (const float*)d_in[0];
    const float* Wqkv = (const float*)d_in[1];
    const float* bqkv = (const float*)d_in[2];
    const float* Wout = (const float*)d_in[3];
    const float* bout = (const float*)d_in[4];
    float* out = (float*)d_out;

    char* ws = (char*)d_ws;
    short* qkvb  = (short*)(ws);                       // 50,331,648 B (V third unused)
    short* VtB   = (short*)(ws + 50331648);            // 16,777,216 B
    short* xTres = (short*)(ws + 67108864);            // 16,777,216 B (xT then res)
    short* WqT   = (short*)(ws + 83886080);            //    786,432 B
    short* WoT   = (short*)(ws + 84672512);            //    262,144 B

    prep<<<dim3(24, 8, 18), 256, 0, stream>>>(Wqkv, Wout, x, WqT, WoT, xTres);
    qkv_gemm<<<dim3(12, 8, 16), 256, 0, stream>>>(xTres, WqT, bqkv, qkvb, VtB);
    attn<<<dim3(512, 1, 1), 512, 0, stream>>>(qkvb, VtB, xTres);
    out_proj<<<dim3(8, 2, 16), 256, 0, stream>>>(WoT, xTres, bout, x, out);
}